// Round 5
// baseline (535.411 us; speedup 1.0000x reference)
//
#include <hip/hip_runtime.h>
#include <hip/hip_bf16.h>

typedef unsigned short u16;
typedef unsigned int u32;
typedef __attribute__((ext_vector_type(8))) short bf16x8_t;   // MFMA A/B frag (8 bf16)
typedef __attribute__((ext_vector_type(4))) float f32x4_t;    // MFMA C/D frag
typedef __attribute__((ext_vector_type(8))) u16 u16x8;
typedef __attribute__((ext_vector_type(4))) u32 u32x4;

// ---- problem constants ----
constexpr int B_  = 8;
constexpr int C_  = 512;
constexpr int NH_ = 16;
constexpr int HID_= 2048;
constexpr int Hh  = 56, Ww = 56;
constexpr int N_  = Hh * Ww;       // 3136
constexpr int M_  = B_ * N_;       // 25088 rows

__device__ __forceinline__ u16 f2bf(float f) {
    u32 u = __float_as_uint(f);
    u32 r = (u + 0x7fffu + ((u >> 16) & 1u)) >> 16;
    return (u16)r;
}
__device__ __forceinline__ float bf2f(u16 v) {
    return __uint_as_float(((u32)v) << 16);
}

// raw barrier: no implicit vmcnt(0) drain. memory clobber pins LDS op order.
__device__ __forceinline__ void bar_raw() {
    __asm__ __volatile__("s_barrier" ::: "memory");
}

// async global->LDS DMA, 16B per lane. LDS dest = wave-uniform base + lane*16.
typedef const void __attribute__((address_space(1))) gvoid_t;
typedef void __attribute__((address_space(3))) lvoid_t;
__device__ __forceinline__ void gload16(const u16* g, u16* l) {
    __builtin_amdgcn_global_load_lds((gvoid_t*)g, (lvoid_t*)l, 16, 0, 0);
}

// ------------------ weight fp32 -> bf16 conversion ------------------
__global__ void cvt_w(const float* __restrict__ qkvw, const float* __restrict__ fc1w,
                      const float* __restrict__ fc2w, u16* __restrict__ oq,
                      u16* __restrict__ o1, u16* __restrict__ o2) {
    int i = blockIdx.x * 256 + threadIdx.x;
    if (i < 3 * C_ * C_) oq[i] = f2bf(qkvw[i]);
    if (i < HID_ * C_) { o1[i] = f2bf(fc1w[i]); o2[i] = f2bf(fc2w[i]); }
}

// ------------------ LayerNorm (row=512) -> bf16 ------------------
__global__ __launch_bounds__(256) void ln_kernel(const float* __restrict__ x,
        const float* __restrict__ g, const float* __restrict__ b, u16* __restrict__ out) {
    int lane = threadIdx.x & 63, wv = threadIdx.x >> 6;
    size_t row = (size_t)blockIdx.x * 4 + wv;
    const float4* xr = (const float4*)(x + row * C_);
    float4 a = xr[lane * 2], c = xr[lane * 2 + 1];
    float s  = a.x + a.y + a.z + a.w + c.x + c.y + c.z + c.w;
    float ss = a.x*a.x + a.y*a.y + a.z*a.z + a.w*a.w + c.x*c.x + c.y*c.y + c.z*c.z + c.w*c.w;
    #pragma unroll
    for (int off = 1; off < 64; off <<= 1) {
        s  += __shfl_xor(s, off);
        ss += __shfl_xor(ss, off);
    }
    float mean = s * (1.0f / C_);
    float var  = ss * (1.0f / C_) - mean * mean;
    float rstd = rsqrtf(var + 1e-5f);
    const float4* g4 = (const float4*)g;
    const float4* b4 = (const float4*)b;
    float4 g0 = g4[lane*2], g1 = g4[lane*2+1], b0 = b4[lane*2], b1 = b4[lane*2+1];
    u16x8 o;
    o[0] = f2bf((a.x - mean) * rstd * g0.x + b0.x);
    o[1] = f2bf((a.y - mean) * rstd * g0.y + b0.y);
    o[2] = f2bf((a.z - mean) * rstd * g0.z + b0.z);
    o[3] = f2bf((a.w - mean) * rstd * g0.w + b0.w);
    o[4] = f2bf((c.x - mean) * rstd * g1.x + b1.x);
    o[5] = f2bf((c.y - mean) * rstd * g1.y + b1.y);
    o[6] = f2bf((c.z - mean) * rstd * g1.z + b1.z);
    o[7] = f2bf((c.w - mean) * rstd * g1.w + b1.w);
    *(u16x8*)&out[row * C_ + lane * 8] = o;
}

// ------------------ bf16 GEMM, 256x256 tile, free-run 3-buffer ring ------------------
// C[M,N] = A[M,K] @ B[N,K]^T + bias (+res). 512 threads = 8 waves (2M x 4N),
// per-wave output 128x64. BK=32: tile t lives in buf t%3 (LDS 96KB total), so
// tile t+2's DMA (issued during iter t) targets tile t-1's buffer, dead since
// bar(t-1) -> ONE barrier per K-tile; within a tile waves FREE-RUN so one wave's
// ds_read service overlaps another's MFMA (LDS pipe || MFMA pipe, m114). vmcnt(4)
// per tile (retires tile t+1; t+2 stays in flight), vmcnt(0) only at the tail.
// setprio(1) wraps each 8-MFMA cluster (role diversity exists now -> T5 applies).
// Staging swizzle = round-0-verified XOR pattern (0 bank conflicts): global chunk
// pre-swizzled per lane, LDS written linearly by DMA, ds_read applies same XOR.
// Race screen: writes of buf b occur in (bar(t-3),bar(t-2)); reads of buf b in
// (bar(t-1),bar(t)) -> barrier-separated. Per-wave vmcnt before bar => all waves'
// DMA of tile t published at bar(t-1) before any wave reads tile t.
template<bool RES, bool OUT_BF16>
__global__ __launch_bounds__(512) void gemm256(
        const u16* __restrict__ A, const u16* __restrict__ B,
        const float* __restrict__ bias, const float* __restrict__ res,
        void* __restrict__ Cout, int M, int N, int K,
        int nbm, int nbn) {
    const int nwg = nbm * nbn;
    const int id = blockIdx.x;
    const int xcd = id & 7, ii = id >> 3;
    const int q = nwg >> 3, r = nwg & 7;
    const int gidx = (xcd < r ? xcd * (q + 1) : r * (q + 1) + (xcd - r) * q) + ii;
    const int bm = gidx / nbn;
    const int bn = gidx - bm * nbn;

    __shared__ __align__(16) u16 As[3 * 8192];   // 48KB: 3 bufs x (2 half x 128r x 32k)
    __shared__ __align__(16) u16 Bs[3 * 8192];   // 48KB
    const int tid = threadIdx.x;
    const int lane = tid & 63;
    const int w = tid >> 6;                // wave 0..7
    const int wm = w >> 2, wn = w & 3;     // 2M x 4N wave grid

    const int r0 = lane >> 2;                          // staging row within 16-row group
    const int gcb = ((lane & 3) ^ ((lane >> 3) & 3));  // swizzled global chunk
    const int fr = lane & 15;                          // fragment row
    const int g4 = lane >> 4;                          // k-chunk index
    const int swz = (g4 ^ ((fr >> 1) & 3)) * 8;        // swizzled element offset
    const int bhf = wn >> 1;                           // B row-half for this wave
    const int bg0 = (wn & 1) * 4;                      // B rowgroup base within half

    // per-thread staging source base (row = w*16+r0 of the tile panel, chunk gcb)
    const u16* aSrc = A + (size_t)(bm * 256 + w * 16 + r0) * K + gcb * 8;
    const u16* bSrc = B + (size_t)(bn * 256 + w * 16 + r0) * K + gcb * 8;
    const size_t hstep = (size_t)128 * K;              // half-tile row step

    f32x4_t acc[2][2][4][2];               // [qm][qn][mf][nf]
    f32x4_t zero = {0.f, 0.f, 0.f, 0.f};
    #pragma unroll
    for (int a0 = 0; a0 < 2; a0++)
        #pragma unroll
        for (int b0 = 0; b0 < 2; b0++)
            #pragma unroll
            for (int c0 = 0; c0 < 4; c0++)
                #pragma unroll
                for (int d0 = 0; d0 < 2; d0++) acc[a0][b0][c0][d0] = zero;

    // stage one half (128 rows x 32 k) of tile u into ring slot cb: 1 op/thread
    auto stageA = [&](int u, int hf, int cb) {
        gload16(aSrc + (size_t)hf * hstep + u * 32, &As[cb + hf * 4096 + w * 512]);
    };
    auto stageB = [&](int u, int hf, int cb) {
        gload16(bSrc + (size_t)hf * hstep + u * 32, &Bs[cb + hf * 4096 + w * 512]);
    };

#define RD_A(DST, CB, QM)                                                      \
    _Pragma("unroll")                                                          \
    for (int mf = 0; mf < 4; mf++)                                             \
        DST[mf] = *(const bf16x8_t*)&As[(CB) + wm * 4096                       \
                        + ((QM) * 64 + mf * 16 + fr) * 32 + swz];

#define RD_B(DST, CB, QN)                                                      \
    _Pragma("unroll")                                                          \
    for (int nf = 0; nf < 2; nf++)                                             \
        DST[nf] = *(const bf16x8_t*)&Bs[(CB) + bhf * 4096                      \
                        + ((bg0 + (QN) * 2 + nf) * 16 + fr) * 32 + swz];

#define MMAC(QM, QN, AR, BR)                                                   \
    __builtin_amdgcn_s_setprio(1);                                             \
    _Pragma("unroll")                                                          \
    for (int mf = 0; mf < 4; mf++)                                             \
        _Pragma("unroll")                                                      \
        for (int nf = 0; nf < 2; nf++)                                         \
            acc[QM][QN][mf][nf] = __builtin_amdgcn_mfma_f32_16x16x32_bf16(     \
                AR[mf], BR[nf], acc[QM][QN][mf][nf], 0, 0, 0);                 \
    __builtin_amdgcn_s_setprio(0);

    const int NT = K >> 5;                 // 32-k tiles (K % 32 == 0 all call sites)
    // prologue: tile0 -> buf0, tile1 -> buf1 (4 ops each); counted wait for tile0
    stageA(0, 0, 0); stageA(0, 1, 0); stageB(0, 0, 0); stageB(0, 1, 0);
    stageA(1, 0, 8192); stageA(1, 1, 8192); stageB(1, 0, 8192); stageB(1, 1, 8192);
    __asm__ __volatile__("s_waitcnt vmcnt(4)" ::: "memory");   // tile0 complete
    bar_raw();

    int cr = 0;                            // read slot  = (t%3)*8192
    int cs = 2 * 8192;                     // stage slot = ((t+2)%3)*8192
    bf16x8_t af0[4], af1[4], bq0[2], bq1[2];

    for (int t = 0; t < NT; t++) {
        // boundary reads (tile t fully published by bar): qm=0 A + both B groups
        RD_A(af0, cr, 0);
        RD_B(bq0, cr, 0);
        RD_B(bq1, cr, 1);
        const bool st = (t + 2 < NT);
        // free-run quadrant phases; 1 stage op interleaved per phase
        MMAC(0, 0, af0, bq0);
        if (st) stageA(t + 2, 0, cs);
        MMAC(0, 1, af0, bq1);
        RD_A(af1, cr, 1);
        if (st) stageA(t + 2, 1, cs);
        MMAC(1, 1, af1, bq1);
        if (st) stageB(t + 2, 0, cs);
        MMAC(1, 0, af1, bq0);
        if (st) stageB(t + 2, 1, cs);
        if (t == NT - 1) break;
        if (st) {
            __asm__ __volatile__("s_waitcnt vmcnt(4)" ::: "memory");  // tile t+1 landed
        } else {
            __asm__ __volatile__("s_waitcnt vmcnt(0)" ::: "memory");  // tail drain
        }
        bar_raw();
        cr = (cr == 2 * 8192) ? 0 : cr + 8192;
        cs = (cs == 2 * 8192) ? 0 : cs + 8192;
    }

#undef RD_A
#undef RD_B
#undef MMAC

    // epilogue: C/D layout col=lane&15, row=(lane>>4)*4+rr (round-0 verified)
    #pragma unroll
    for (int qm = 0; qm < 2; qm++)
        #pragma unroll
        for (int qn = 0; qn < 2; qn++)
            #pragma unroll
            for (int mf = 0; mf < 4; mf++)
                #pragma unroll
                for (int rr = 0; rr < 4; rr++) {
                    int row = bm * 256 + wm * 128 + qm * 64 + mf * 16 + (lane >> 4) * 4 + rr;
                    #pragma unroll
                    for (int nf = 0; nf < 2; nf++) {
                        int col = bn * 256 + wn * 64 + qn * 32 + nf * 16 + (lane & 15);
                        float v = acc[qm][qn][mf][nf][rr] + bias[col];
                        if constexpr (RES) v += res[(size_t)row * N + col];
                        if constexpr (OUT_BF16) ((u16*)Cout)[(size_t)row * N + col] = f2bf(v);
                        else ((float*)Cout)[(size_t)row * N + col] = v;
                    }
                }
}

// ------------------ windowed attention, one block per (window, head) ------------------
// Writes compact bf16 out: [win(512), head(16), 49, 32]
constexpr int QS = 40;  // q/k row stride (u16), padded +8
constexpr int VS = 72;  // vT row stride
constexpr int PS = 72;  // p row stride

__global__ __launch_bounds__(256) void attn_kernel(
        const u16* __restrict__ qkv, const float* __restrict__ rpb,
        u16* __restrict__ aout) {
    __shared__ __align__(16) u16 q_s[64 * QS];
    __shared__ __align__(16) u16 k_s[64 * QS];
    __shared__ __align__(16) u16 vT_s[32 * VS];
    __shared__ __align__(16) u16 p_s[64 * PS];
    const int tid = threadIdx.x, lane = tid & 63, wv = tid >> 6;
    const int wh = blockIdx.x;
    const int head = wh & 15, w = wh >> 4;
    const int b = w >> 6, win = w & 63, bh = win >> 3, bw = win & 7;

    // load q,k padded to 64 rows
    {
        int i = tid >> 2, dc = (tid & 3) * 8;
        if (i < 49) {
            int n = (bh * 7 + i / 7) * Ww + (bw * 7 + i % 7);
            const u16* base = qkv + ((size_t)(b * N_ + n)) * (3 * C_) + head * 32 + dc;
            *(u16x8*)&q_s[i * QS + dc] = *(const u16x8*)(base);
            *(u16x8*)&k_s[i * QS + dc] = *(const u16x8*)(base + C_);
        } else {
            u16x8 z = {0,0,0,0,0,0,0,0};
            *(u16x8*)&q_s[i * QS + dc] = z;
            *(u16x8*)&k_s[i * QS + dc] = z;
        }
    }
    // v transposed: vT[d][i]
    for (int f = tid; f < 64 * 32; f += 256) {
        int i = f >> 5, d = f & 31;
        u16 val = 0;
        if (i < 49) {
            int n = (bh * 7 + i / 7) * Ww + (bw * 7 + i % 7);
            val = qkv[((size_t)(b * N_ + n)) * (3 * C_) + 2 * C_ + head * 32 + d];
        }
        vT_s[d * VS + i] = val;
    }
    __syncthreads();

    // S = q @ k^T (wave wv owns rows wv*16..+16)
    f32x4_t zero = {0.f, 0.f, 0.f, 0.f};
    f32x4_t s[4];
    bf16x8_t aq = *(const bf16x8_t*)&q_s[(wv * 16 + (lane & 15)) * QS + (lane >> 4) * 8];
    #pragma unroll
    for (int nt = 0; nt < 4; nt++) {
        bf16x8_t bk = *(const bf16x8_t*)&k_s[(nt * 16 + (lane & 15)) * QS + (lane >> 4) * 8];
        s[nt] = __builtin_amdgcn_mfma_f32_16x16x32_bf16(aq, bk, zero, 0, 0, 0);
    }

    const float scale = 0.17677669529663687f; // 32^-0.5
    #pragma unroll
    for (int r = 0; r < 4; r++) {
        int row = wv * 16 + (lane >> 4) * 4 + r;
        int qy = row / 7, qx = row - qy * 7;
        float pv[4];
        float m = -1e30f;
        #pragma unroll
        for (int nt = 0; nt < 4; nt++) {
            int col = nt * 16 + (lane & 15);
            float bias;
            if (row < 49 && col < 49) {
                int ky = col / 7, kx = col - ky * 7;
                bias = rpb[((qy - ky + 6) * 13 + (qx - kx + 6)) * NH_ + head];
            } else bias = -1e30f;
            float v = s[nt][r] * scale + bias;
            pv[nt] = v;
            m = fmaxf(m, v);
        }
        #pragma unroll
        for (int off = 1; off < 16; off <<= 1) m = fmaxf(m, __shfl_xor(m, off));
        float sum = 0.f;
        #pragma unroll
        for (int nt = 0; nt < 4; nt++) { pv[nt] = __expf(pv[nt] - m); sum += pv[nt]; }
        #pragma unroll
        for (int off = 1; off < 16; off <<= 1) sum += __shfl_xor(sum, off);
        float inv = 1.0f / sum;
        #pragma unroll
        for (int nt = 0; nt < 4; nt++)
            p_s[row * PS + nt * 16 + (lane & 15)] = f2bf(pv[nt] * inv);
    }
    __syncthreads();

    // O = P @ V (rows wv*16..+16, cols 0..31)
    f32x4_t o[2] = {zero, zero};
    #pragma unroll
    for (int kt = 0; kt < 2; kt++) {
        bf16x8_t ap = *(const bf16x8_t*)&p_s[(wv * 16 + (lane & 15)) * PS + kt * 32 + (lane >> 4) * 8];
        #pragma unroll
        for (int nt = 0; nt < 2; nt++) {
            bf16x8_t bv = *(const bf16x8_t*)&vT_s[(nt * 16 + (lane & 15)) * VS + kt * 32 + (lane >> 4) * 8];
            o[nt] = __builtin_amdgcn_mfma_f32_16x16x32_bf16(ap, bv, o[nt], 0, 0, 0);
        }
    }
    // compact write: aout[((w*16+head)*49 + row)*32 + col]
    u16* obase = aout + ((size_t)(w * 16 + head)) * 49 * 32;
    #pragma unroll
    for (int nt = 0; nt < 2; nt++) {
        #pragma unroll
        for (int r = 0; r < 4; r++) {
            int row = wv * 16 + (lane >> 4) * 4 + r;
            if (row < 49)
                obase[row * 32 + nt * 16 + (lane & 15)] = f2bf(o[nt][r]);
        }
    }
}

// ------------------ window-reverse + residual + LayerNorm2 (fused) ------------------
__global__ __launch_bounds__(256) void wrev_ln(const float* __restrict__ x,
        const u16* __restrict__ aout, const float* __restrict__ g,
        const float* __restrict__ bt, float* __restrict__ x2, u16* __restrict__ h) {
    int lane = threadIdx.x & 63, wvv = threadIdx.x >> 6;
    int m = blockIdx.x * 4 + wvv;
    int b = m / N_, n = m - b * N_;
    int iy = n / Ww, ix = n - iy * Ww;
    int w = b * 64 + (iy / 7) * 8 + (ix / 7);
    int pos = (iy % 7) * 7 + (ix % 7);
    int head = lane >> 2, d0 = (lane & 3) * 8;
    u16x8 ao = *(const u16x8*)&aout[(((size_t)w * 16 + head) * 49 + pos) * 32 + d0];
    const float4* xr = (const float4*)(x + (size_t)m * C_ + lane * 8);
    float4 a = xr[0], c = xr[1];
    float v[8];
    v[0] = a.x + bf2f(ao[0]); v[1] = a.y + bf2f(ao[1]);
    v[2] = a.z + bf2f(ao[2]); v[3] = a.w + bf2f(ao[3]);
    v[4] = c.x + bf2f(ao[4]); v[5] = c.y + bf2f(ao[5]);
    v[6] = c.z + bf2f(ao[6]); v[7] = c.w + bf2f(ao[7]);
    float s = 0.f, ss = 0.f;
    #pragma unroll
    for (int jj = 0; jj < 8; jj++) { s += v[jj]; ss += v[jj] * v[jj]; }
    #pragma unroll
    for (int off = 1; off < 64; off <<= 1) {
        s  += __shfl_xor(s, off);
        ss += __shfl_xor(ss, off);
    }
    float mean = s * (1.0f / C_);
    float var  = ss * (1.0f / C_) - mean * mean;
    float rstd = rsqrtf(var + 1e-5f);
    float4 o0 = {v[0], v[1], v[2], v[3]}, o1 = {v[4], v[5], v[6], v[7]};
    float4* x2r = (float4*)(x2 + (size_t)m * C_ + lane * 8);
    x2r[0] = o0; x2r[1] = o1;
    const float4* g4 = (const float4*)(g + lane * 8);
    const float4* b4 = (const float4*)(bt + lane * 8);
    float4 g0 = g4[0], g1 = g4[1], bb0 = b4[0], bb1 = b4[1];
    u16x8 o;
    o[0] = f2bf((v[0] - mean) * rstd * g0.x + bb0.x);
    o[1] = f2bf((v[1] - mean) * rstd * g0.y + bb0.y);
    o[2] = f2bf((v[2] - mean) * rstd * g0.z + bb0.z);
    o[3] = f2bf((v[3] - mean) * rstd * g0.w + bb0.w);
    o[4] = f2bf((v[4] - mean) * rstd * g1.x + bb1.x);
    o[5] = f2bf((v[5] - mean) * rstd * g1.y + bb1.y);
    o[6] = f2bf((v[6] - mean) * rstd * g1.z + bb1.z);
    o[7] = f2bf((v[7] - mean) * rstd * g1.w + bb1.w);
    *(u16x8*)&h[(size_t)m * C_ + lane * 8] = o;
}

// ------------------ depthwise 3x3 conv + bias + exact GELU (y-pair blocked) ------------------
__global__ __launch_bounds__(256) void dwconv_gelu(const u16* __restrict__ in,
        const float* __restrict__ w, const float* __restrict__ bias, u16* __restrict__ out) {
    const int t = threadIdx.x;
    const int blk = blockIdx.x;
    const int xq = blk & 3;
    const int byp = blk >> 2;
    const int yp = byp % 28;
    const int b = byp / 28;
    const int y0 = yp * 2;
    const int c0 = t * 8;

    float wr[9][8];
    #pragma unroll
    for (int k = 0; k < 9; k++)
        #pragma unroll
        for (int j = 0; j < 8; j++) wr[k][j] = w[(c0 + j) * 9 + k];
    float bs[8];
    #pragma unroll
    for (int j = 0; j < 8; j++) bs[j] = bias[c0 + j];

    u16x8 zerov = {0,0,0,0,0,0,0,0};
    auto ldcol = [&](int xx, u16x8* col) {
        #pragma unroll
        for (int dy = 0; dy < 4; dy++) {
            int yy = y0 + dy - 1;
            bool ok = (yy >= 0 && yy < Hh && xx >= 0 && xx < Ww);
            col[dy] = ok ? *(const u16x8*)&in[(((size_t)b * Hh + yy) * Ww + xx) * HID_ + c0] : zerov;
        }
    };

    int xs = xq * 14;
    u16x8 wA[4], wB[4], wC[4];
    ldcol(xs - 1, wA);
    ldcol(xs, wB);
    for (int x = xs; x < xs + 14; x++) {
        ldcol(x + 1, wC);
        float acc0[8], acc1[8];
        #pragma unroll
        for (int j = 0; j < 8; j++) { acc0[j] = bs[j]; acc1[j] = bs[j]; }
        #pragma unroll
        for (int dy = 0; dy < 3; dy++)
            #pragma unroll
            for (int j = 0; j < 8; j++) {
                acc0[j] += bf2f(wA[dy][j]) * wr[dy * 3 + 0][j];
                acc0[j] += bf2f(wB[dy][j]) * wr[dy * 3 + 1][j];
                acc0[j] += bf2f(wC[dy][j]) * wr[dy * 3 + 2][j];
                acc1[j] += bf2f(wA[dy + 1][j]) * wr[dy * 3 + 0][j];
                acc1[j] += bf2f(wB[dy + 1][j]) * wr[dy * 3 + 1][j];
                acc1[j] += bf2f(wC[dy + 1][j]) * wr[dy * 3 + 2][j];
            }
        u16x8 o0, o1;
        #pragma unroll
        for (int j = 0; j < 8; j++) {
            float v0 = acc0[j];
            o0[j] = f2bf(0.5f * v0 * (1.0f + erff(v0 * 0.70710678118654752f)));
            float v1 = acc1[j];
            o1[j] = f2bf(0.5f * v1 * (1.0f + erff(v1 * 0.70710678118654752f)));
        }
        *(u16x8*)&out[(((size_t)b * Hh + y0) * Ww + x) * HID_ + c0] = o0;
        *(u16x8*)&out[(((size_t)b * Hh + y0 + 1) * Ww + x) * HID_ + c0] = o1;
        #pragma unroll
        for (int dy = 0; dy < 4; dy++) { wA[dy] = wB[dy]; wB[dy] = wC[dy]; }
    }
}

// ------------------ launch ------------------
extern "C" void kernel_launch(void* const* d_in, const int* in_sizes, int n_in,
                              void* d_out, int out_size, void* d_ws, size_t ws_size,
                              hipStream_t stream) {
    const float* x    = (const float*)d_in[0];
    const float* n1g  = (const float*)d_in[3];
    const float* n1b  = (const float*)d_in[4];
    const float* n2g  = (const float*)d_in[5];
    const float* n2b  = (const float*)d_in[6];
    const float* qkvw = (const float*)d_in[7];
    const float* qkvb = (const float*)d_in[8];
    const float* rpb  = (const float*)d_in[9];
    const float* fc1w = (const float*)d_in[10];
    const float* fc1b = (const float*)d_in[11];
    const float* dww  = (const float*)d_in[12];
    const float* dwb  = (const float*)d_in[13];
    const float* fc2w = (const float*)d_in[14];
    const float* fc2b = (const float*)d_in[15];

    char* ws = (char*)d_ws;
    float* x2  = (float*)(ws);
    u16*   h   = (u16*)(ws + 51380224);
    u16*   qkvo= (u16*)(ws + 77070336);
    u16*   aout= (u16*)(ws + 154140672);
    u16*   f1o = (u16*)(ws + 154140672);
    u16*   cvo = (u16*)(ws + 51380224);
    u16*   wq  = (u16*)(ws + 256901120);
    u16*   w1  = (u16*)(ws + 256901120 + 1572864);
    u16*   w2  = (u16*)(ws + 256901120 + 1572864 + 2097152);

    cvt_w<<<dim3(4096), dim3(256), 0, stream>>>(qkvw, fc1w, fc2w, wq, w1, w2);
    ln_kernel<<<dim3(M_ / 4), dim3(256), 0, stream>>>(x, n1g, n1b, h);
    // qkv: M=25088 N=1536 K=512 -> nbm=98, nbn=6 -> 588 blocks
    gemm256<false, true><<<dim3(588), dim3(512), 0, stream>>>(
        h, wq, qkvb, nullptr, (void*)qkvo, M_, 1536, 512, 98, 6);
    attn_kernel<<<dim3(B_ * 64 * NH_), dim3(256), 0, stream>>>(qkvo, rpb, aout);
    wrev_ln<<<dim3(M_ / 4), dim3(256), 0, stream>>>(x, aout, n2g, n2b, x2, h);
    // fc1: N=2048 K=512 -> 98x8 = 784 blocks
    gemm256<false, true><<<dim3(784), dim3(512), 0, stream>>>(
        h, w1, fc1b, nullptr, (void*)f1o, M_, 2048, 512, 98, 8);
    dwconv_gelu<<<dim3(B_ * 28 * 4), dim3(256), 0, stream>>>(f1o, dww, dwb, cvo);
    // fc2: N=512 K=2048 -> 98x2 = 196 blocks
    gemm256<true, false><<<dim3(196), dim3(512), 0, stream>>>(
        cvo, w2, fc2b, x2, d_out, M_, 512, 2048, 98, 2);
}

// Round 6
// 475.483 us; speedup vs baseline: 1.1260x; 1.1260x over previous
//
#include <hip/hip_runtime.h>
#include <hip/hip_bf16.h>

typedef unsigned short u16;
typedef unsigned int u32;
typedef __attribute__((ext_vector_type(8))) short bf16x8_t;   // MFMA A/B frag (8 bf16)
typedef __attribute__((ext_vector_type(4))) float f32x4_t;    // MFMA C/D frag
typedef __attribute__((ext_vector_type(8))) u16 u16x8;
typedef __attribute__((ext_vector_type(4))) u32 u32x4;

// ---- problem constants ----
constexpr int B_  = 8;
constexpr int C_  = 512;
constexpr int NH_ = 16;
constexpr int HID_= 2048;
constexpr int Hh  = 56, Ww = 56;
constexpr int N_  = Hh * Ww;       // 3136
constexpr int M_  = B_ * N_;       // 25088 rows

__device__ __forceinline__ u16 f2bf(float f) {
    u32 u = __float_as_uint(f);
    u32 r = (u + 0x7fffu + ((u >> 16) & 1u)) >> 16;
    return (u16)r;
}
__device__ __forceinline__ float bf2f(u16 v) {
    return __uint_as_float(((u32)v) << 16);
}

// raw barrier: no implicit vmcnt(0) drain. memory clobber pins LDS op order.
__device__ __forceinline__ void bar_raw() {
    __asm__ __volatile__("s_barrier" ::: "memory");
}
// barrier that first drains LDS ops only (lgkmcnt(0), vmcnt untouched).
__device__ __forceinline__ void bar_lgkm() {
    __builtin_amdgcn_s_waitcnt(0xc07f);
    __asm__ __volatile__("s_barrier" ::: "memory");
}

// async global->LDS DMA, 16B per lane. LDS dest = wave-uniform base + lane*16.
typedef const void __attribute__((address_space(1))) gvoid_t;
typedef void __attribute__((address_space(3))) lvoid_t;
__device__ __forceinline__ void gload16(const u16* g, u16* l) {
    __builtin_amdgcn_global_load_lds((gvoid_t*)g, (lvoid_t*)l, 16, 0, 0);
}

// ------------------ fused: weight cvt + LayerNorm1 (saves one launch) ------------------
// blocks [0, M_/4): LN rows; blocks [M_/4, M_/4+4096): weight fp32->bf16 cvt.
__global__ __launch_bounds__(256) void cvt_ln(
        const float* __restrict__ x, const float* __restrict__ g, const float* __restrict__ b,
        u16* __restrict__ out,
        const float* __restrict__ qkvw, const float* __restrict__ fc1w,
        const float* __restrict__ fc2w, u16* __restrict__ oq,
        u16* __restrict__ o1, u16* __restrict__ o2) {
    if (blockIdx.x >= (M_ / 4)) {
        int i = (blockIdx.x - M_ / 4) * 256 + threadIdx.x;
        if (i < 3 * C_ * C_) oq[i] = f2bf(qkvw[i]);
        if (i < HID_ * C_) { o1[i] = f2bf(fc1w[i]); o2[i] = f2bf(fc2w[i]); }
        return;
    }
    int lane = threadIdx.x & 63, wv = threadIdx.x >> 6;
    size_t row = (size_t)blockIdx.x * 4 + wv;
    const float4* xr = (const float4*)(x + row * C_);
    float4 a = xr[lane * 2], c = xr[lane * 2 + 1];
    float s  = a.x + a.y + a.z + a.w + c.x + c.y + c.z + c.w;
    float ss = a.x*a.x + a.y*a.y + a.z*a.z + a.w*a.w + c.x*c.x + c.y*c.y + c.z*c.z + c.w*c.w;
    #pragma unroll
    for (int off = 1; off < 64; off <<= 1) {
        s  += __shfl_xor(s, off);
        ss += __shfl_xor(ss, off);
    }
    float mean = s * (1.0f / C_);
    float var  = ss * (1.0f / C_) - mean * mean;
    float rstd = rsqrtf(var + 1e-5f);
    const float4* g4 = (const float4*)g;
    const float4* b4 = (const float4*)b;
    float4 g0 = g4[lane*2], g1 = g4[lane*2+1], b0 = b4[lane*2], b1 = b4[lane*2+1];
    u16x8 o;
    o[0] = f2bf((a.x - mean) * rstd * g0.x + b0.x);
    o[1] = f2bf((a.y - mean) * rstd * g0.y + b0.y);
    o[2] = f2bf((a.z - mean) * rstd * g0.z + b0.z);
    o[3] = f2bf((a.w - mean) * rstd * g0.w + b0.w);
    o[4] = f2bf((c.x - mean) * rstd * g1.x + b1.x);
    o[5] = f2bf((c.y - mean) * rstd * g1.y + b1.y);
    o[6] = f2bf((c.z - mean) * rstd * g1.z + b1.z);
    o[7] = f2bf((c.w - mean) * rstd * g1.w + b1.w);
    *(u16x8*)&out[row * C_ + lane * 8] = o;
}

// ------------------ bf16 GEMM (128x128 tile, reg-staged pipeline) ------------------
// Round-0 verified kernel: best for short-K GEMMs (qkv, fc1) — 3 blocks/CU and
// loads for tile k+1 issued before the MFMA block of tile k (reg pipeline).
template<bool RES, bool OUT_BF16>
__global__ __launch_bounds__(256) void gemm_bt(
        const u16* __restrict__ A, const u16* __restrict__ B,
        const float* __restrict__ bias, const float* __restrict__ res,
        void* __restrict__ Cout, int M, int N, int K,
        int nbm, int nbn, int nGroups) {
    const int id = blockIdx.x;
    const int xcd = id & 7, slot = id >> 3;
    const int j = slot & 3;
    const int gidx = xcd + 8 * (slot >> 2);
    if (gidx >= nGroups) return;
    const int bm = gidx % nbm;
    const int bn = (gidx / nbm) * 4 + j;
    if (bn >= nbn) return;

    __shared__ __align__(16) u16 As[2 * 128 * 32];
    __shared__ __align__(16) u16 Bs[2 * 128 * 32];
    const int tid = threadIdx.x;
    const int lane = tid & 63;
    const int wv = tid >> 6;

    const int r0 = lane >> 2;                          // staging row within 16-row group
    const int gcb = ((lane & 3) ^ ((lane >> 3) & 3));  // swizzled global chunk for this lane

    const u16* aBase = A + (size_t)(bm * 128) * K;
    const u16* bBase = B + (size_t)(bn * 128) * K;

    f32x4_t acc[4][4];
    f32x4_t zero = {0.f, 0.f, 0.f, 0.f};
    #pragma unroll
    for (int i = 0; i < 4; i++)
        #pragma unroll
        for (int jj = 0; jj < 4; jj++) acc[i][jj] = zero;

    const int mo = (wv >> 1) * 64, no = (wv & 1) * 64;
    const int fr = lane & 15;          // fragment row (m or n)
    const int g4 = lane >> 4;          // k-chunk index within 32-k plane
    const int kkey = (fr >> 1) & 3;    // swizzle key
    const int pos = (g4 ^ kkey) * 8;   // swizzled element offset within row

    u32x4 ra[2][2], rb[2][2];
    auto ldissue = [&](int k0) {
        #pragma unroll
        for (int p = 0; p < 2; p++)
            #pragma unroll
            for (int jj = 0; jj < 2; jj++) {
                const int ko = k0 + p * 32 + gcb * 8;
                ra[p][jj] = *(const u32x4*)(aBase + (size_t)((wv + jj * 4) * 16 + r0) * K + ko);
                rb[p][jj] = *(const u32x4*)(bBase + (size_t)((wv + jj * 4) * 16 + r0) * K + ko);
            }
    };
    auto dswrite = [&]() {
        #pragma unroll
        for (int p = 0; p < 2; p++)
            #pragma unroll
            for (int jj = 0; jj < 2; jj++) {
                ((u32x4*)&As[p * 4096 + (wv + jj * 4) * 16 * 32])[lane] = ra[p][jj];
                ((u32x4*)&Bs[p * 4096 + (wv + jj * 4) * 16 * 32])[lane] = rb[p][jj];
            }
    };

    ldissue(0);
    for (int k0 = 0; k0 < K; k0 += 64) {
        dswrite();                 // vmcnt wait lands here (one full iteration after issue)
        bar_lgkm();                // ds_writes visible; global loads stay in flight
        if (k0 + 64 < K) ldissue(k0 + 64);

        #pragma unroll
        for (int ks = 0; ks < 2; ks++) {
            bf16x8_t af[4], bfr[4];
            #pragma unroll
            for (int mt = 0; mt < 4; mt++)
                af[mt] = *(const bf16x8_t*)&As[ks * 4096 + (mo + mt * 16 + fr) * 32 + pos];
            #pragma unroll
            for (int nt = 0; nt < 4; nt++)
                bfr[nt] = *(const bf16x8_t*)&Bs[ks * 4096 + (no + nt * 16 + fr) * 32 + pos];
            #pragma unroll
            for (int mt = 0; mt < 4; mt++)
                #pragma unroll
                for (int nt = 0; nt < 4; nt++)
                    acc[mt][nt] = __builtin_amdgcn_mfma_f32_16x16x32_bf16(af[mt], bfr[nt], acc[mt][nt], 0, 0, 0);
        }
        bar_raw();                 // all waves done reading before next overwrite
    }

    // epilogue: C/D layout col=lane&15, row=(lane>>4)*4+r
    #pragma unroll
    for (int mt = 0; mt < 4; mt++) {
        #pragma unroll
        for (int r = 0; r < 4; r++) {
            int row = bm * 128 + mo + mt * 16 + (lane >> 4) * 4 + r;
            #pragma unroll
            for (int nt = 0; nt < 4; nt++) {
                int col = bn * 128 + no + nt * 16 + (lane & 15);
                float v = acc[mt][nt][r] + bias[col];
                if constexpr (RES) v += res[(size_t)row * N + col];
                if constexpr (OUT_BF16) ((u16*)Cout)[(size_t)row * N + col] = f2bf(v);
                else ((float*)Cout)[(size_t)row * N + col] = v;
            }
        }
    }
}

// ------------------ bf16 GEMM, 256x256 tile, pipelined 4-phase (round-4) ------------------
// Best for long-K (fc2, K=2048): prologue/epilogue amortized over 32 tiles.
template<bool RES, bool OUT_BF16>
__global__ __launch_bounds__(512) void gemm256(
        const u16* __restrict__ A, const u16* __restrict__ B,
        const float* __restrict__ bias, const float* __restrict__ res,
        void* __restrict__ Cout, int M, int N, int K,
        int nbm, int nbn) {
    const int nwg = nbm * nbn;
    const int id = blockIdx.x;
    const int xcd = id & 7, ii = id >> 3;
    const int q = nwg >> 3, r = nwg & 7;
    const int gidx = (xcd < r ? xcd * (q + 1) : r * (q + 1) + (xcd - r) * q) + ii;
    const int bm = gidx / nbn;
    const int bn = gidx - bm * nbn;

    __shared__ __align__(16) u16 As[2 * 16384];   // 64KB
    __shared__ __align__(16) u16 Bs[2 * 16384];   // 64KB
    const int tid = threadIdx.x;
    const int lane = tid & 63;
    const int w = tid >> 6;                // wave 0..7
    const int wm = w >> 2, wn = w & 3;     // 2M x 4N wave grid

    const int r0 = lane >> 2;                          // staging row within 16-row group
    const int gcb = ((lane & 3) ^ ((lane >> 3) & 3));  // swizzled global chunk
    const int fr = lane & 15;                          // fragment row
    const int g4 = lane >> 4;                          // k-chunk index
    const int swz = (g4 ^ ((fr >> 1) & 3)) * 8;        // swizzled element offset
    const int bhf = wn >> 1;                           // B half for this wave
    const int bg0 = (wn & 1) * 4;                      // B rowgroup base within half

    const u16* aBase = A + (size_t)(bm * 256) * K;
    const u16* bBase = B + (size_t)(bn * 256) * K;

    f32x4_t acc[2][2][4][2];               // [qm][qn][mf][nf]
    f32x4_t zero = {0.f, 0.f, 0.f, 0.f};
    #pragma unroll
    for (int a0 = 0; a0 < 2; a0++)
        #pragma unroll
        for (int b0 = 0; b0 < 2; b0++)
            #pragma unroll
            for (int c0 = 0; c0 < 4; c0++)
                #pragma unroll
                for (int d0 = 0; d0 < 2; d0++) acc[a0][b0][c0][d0] = zero;

    // stage one half-tile (128 rows x 64 k): wave w = rowgroup w, both 32-k planes.
    auto stage = [&](const u16* gb, u16* lb, int u, int hf) {
        const u16* src = gb + (size_t)(hf * 128 + w * 16 + r0) * K
                            + (size_t)(u * 64 + gcb * 8);
        u16* dst = lb + (u & 1) * 16384 + hf * 8192 + w * 512;
        gload16(src, dst);                 // plane 0
        gload16(src + 32, dst + 4096);     // plane 1
    };

#define RD_A(DST, BB, QM)                                                      \
    _Pragma("unroll")                                                          \
    for (int ks = 0; ks < 2; ks++)                                             \
        _Pragma("unroll")                                                      \
        for (int mf = 0; mf < 4; mf++)                                         \
            DST[ks][mf] = *(const bf16x8_t*)&As[(BB) + wm * 8192 + ks * 4096   \
                            + ((QM) * 4 + mf) * 512 + fr * 32 + swz];

#define RD_B(DST, BB, QN)                                                      \
    _Pragma("unroll")                                                          \
    for (int ks = 0; ks < 2; ks++)                                             \
        _Pragma("unroll")                                                      \
        for (int nf = 0; nf < 2; nf++)                                         \
            DST[ks][nf] = *(const bf16x8_t*)&Bs[(BB) + bhf * 8192 + ks * 4096  \
                            + (bg0 + (QN) * 2 + nf) * 512 + fr * 32 + swz];

#define MMAC(QM, QN, AR, BR)                                                   \
    __builtin_amdgcn_s_setprio(1);                                             \
    _Pragma("unroll")                                                          \
    for (int mf = 0; mf < 4; mf++)                                             \
        _Pragma("unroll")                                                      \
        for (int nf = 0; nf < 2; nf++)                                         \
            _Pragma("unroll")                                                  \
            for (int ks = 0; ks < 2; ks++)                                     \
                acc[QM][QN][mf][nf] = __builtin_amdgcn_mfma_f32_16x16x32_bf16( \
                    AR[ks][mf], BR[ks][nf], acc[QM][QN][mf][nf], 0, 0, 0);     \
    __builtin_amdgcn_s_setprio(0);

    const int NT = K >> 6;
    // prologue: tile0 (8 ops) + tile1's PH2/PH3-slot halves (4 ops); counted
    // vmcnt(4): in-order retirement => oldest 8 (tile0) complete.
    stage(aBase, As, 0, 0);
    stage(aBase, As, 0, 1);
    stage(bBase, Bs, 0, 0);
    stage(bBase, Bs, 0, 1);
    stage(bBase, Bs, 1, 0);
    stage(aBase, As, 1, 0);
    __asm__ __volatile__("s_waitcnt vmcnt(4)" ::: "memory");
    bar_raw();

    bf16x8_t afr[2][4], bq0[2][2], bq1[2][2];
    RD_A(afr, 0, 0);
    RD_B(bq0, 0, 0);

    for (int t = 0; t < NT; t++) {
        const int bb = (t & 1) * 16384;
        const int ob = bb ^ 16384;
        // PH0: C(qm0,qn0); prefetch B-qn1; stage A[t+1]h1
        MMAC(0, 0, afr, bq0);
        RD_B(bq1, bb, 1);
        if (t + 1 < NT) stage(aBase, As, t + 1, 1);
        bar_raw();
        // PH1: C(qm0,qn1); prefetch A-qm1 (afr reuse, qm0 dead); stage B[t+1]h1
        MMAC(0, 1, afr, bq1);
        RD_A(afr, bb, 1);
        if (t + 1 < NT) stage(bBase, Bs, t + 1, 1);
        bar_raw();
        // PH2: C(qm1,qn1); stage B[t+2]h0
        MMAC(1, 1, afr, bq1);
        if (t + 2 < NT) stage(bBase, Bs, t + 2, 0);
        bar_raw();
        // PH3: C(qm1,qn0); stage A[t+2]h0; counted vmcnt -> tile t+1 landed
        MMAC(1, 0, afr, bq0);
        if (t + 2 < NT) {
            stage(aBase, As, t + 2, 0);
            __asm__ __volatile__("s_waitcnt vmcnt(4)" ::: "memory");
        } else if (t + 1 < NT) {
            __asm__ __volatile__("s_waitcnt vmcnt(0)" ::: "memory");  // tail: <4 newer ops
        }
        bar_raw();
        // tile-boundary prefetch: next tile's PH0 fragments
        if (t + 1 < NT) {
            RD_A(afr, ob, 0);
            RD_B(bq0, ob, 0);
        }
    }

#undef RD_A
#undef RD_B
#undef MMAC

    // epilogue: C/D layout col=lane&15, row=(lane>>4)*4+rr
    #pragma unroll
    for (int qm = 0; qm < 2; qm++)
        #pragma unroll
        for (int qn = 0; qn < 2; qn++)
            #pragma unroll
            for (int mf = 0; mf < 4; mf++)
                #pragma unroll
                for (int rr = 0; rr < 4; rr++) {
                    int row = bm * 256 + wm * 128 + qm * 64 + mf * 16 + (lane >> 4) * 4 + rr;
                    #pragma unroll
                    for (int nf = 0; nf < 2; nf++) {
                        int col = bn * 256 + wn * 64 + qn * 32 + nf * 16 + (lane & 15);
                        float v = acc[qm][qn][mf][nf][rr] + bias[col];
                        if constexpr (RES) v += res[(size_t)row * N + col];
                        if constexpr (OUT_BF16) ((u16*)Cout)[(size_t)row * N + col] = f2bf(v);
                        else ((float*)Cout)[(size_t)row * N + col] = v;
                    }
                }
}

// ------------------ windowed attention, one block per (window, head) ------------------
// Writes compact bf16 out: [win(512), head(16), 49, 32]
constexpr int QS = 40;  // q/k row stride (u16), padded +8
constexpr int VS = 72;  // vT row stride
constexpr int PS = 72;  // p row stride

__global__ __launch_bounds__(256) void attn_kernel(
        const u16* __restrict__ qkv, const float* __restrict__ rpb,
        u16* __restrict__ aout) {
    __shared__ __align__(16) u16 q_s[64 * QS];
    __shared__ __align__(16) u16 k_s[64 * QS];
    __shared__ __align__(16) u16 vT_s[32 * VS];
    __shared__ __align__(16) u16 p_s[64 * PS];
    const int tid = threadIdx.x, lane = tid & 63, wv = tid >> 6;
    const int wh = blockIdx.x;
    const int head = wh & 15, w = wh >> 4;
    const int b = w >> 6, win = w & 63, bh = win >> 3, bw = win & 7;

    // load q,k padded to 64 rows
    {
        int i = tid >> 2, dc = (tid & 3) * 8;
        if (i < 49) {
            int n = (bh * 7 + i / 7) * Ww + (bw * 7 + i % 7);
            const u16* base = qkv + ((size_t)(b * N_ + n)) * (3 * C_) + head * 32 + dc;
            *(u16x8*)&q_s[i * QS + dc] = *(const u16x8*)(base);
            *(u16x8*)&k_s[i * QS + dc] = *(const u16x8*)(base + C_);
        } else {
            u16x8 z = {0,0,0,0,0,0,0,0};
            *(u16x8*)&q_s[i * QS + dc] = z;
            *(u16x8*)&k_s[i * QS + dc] = z;
        }
    }
    // v transposed: vT[d][i]
    for (int f = tid; f < 64 * 32; f += 256) {
        int i = f >> 5, d = f & 31;
        u16 val = 0;
        if (i < 49) {
            int n = (bh * 7 + i / 7) * Ww + (bw * 7 + i % 7);
            val = qkv[((size_t)(b * N_ + n)) * (3 * C_) + 2 * C_ + head * 32 + d];
        }
        vT_s[d * VS + i] = val;
    }
    __syncthreads();

    // S = q @ k^T (wave wv owns rows wv*16..+16)
    f32x4_t zero = {0.f, 0.f, 0.f, 0.f};
    f32x4_t s[4];
    bf16x8_t aq = *(const bf16x8_t*)&q_s[(wv * 16 + (lane & 15)) * QS + (lane >> 4) * 8];
    #pragma unroll
    for (int nt = 0; nt < 4; nt++) {
        bf16x8_t bk = *(const bf16x8_t*)&k_s[(nt * 16 + (lane & 15)) * QS + (lane >> 4) * 8];
        s[nt] = __builtin_amdgcn_mfma_f32_16x16x32_bf16(aq, bk, zero, 0, 0, 0);
    }

    const float scale = 0.17677669529663687f; // 32^-0.5
    #pragma unroll
    for (int r = 0; r < 4; r++) {
        int row = wv * 16 + (lane >> 4) * 4 + r;
        int qy = row / 7, qx = row - qy * 7;
        float pv[4];
        float m = -1e30f;
        #pragma unroll
        for (int nt = 0; nt < 4; nt++) {
            int col = nt * 16 + (lane & 15);
            float bias;
            if (row < 49 && col < 49) {
                int ky = col / 7, kx = col - ky * 7;
                bias = rpb[((qy - ky + 6) * 13 + (qx - kx + 6)) * NH_ + head];
            } else bias = -1e30f;
            float v = s[nt][r] * scale + bias;
            pv[nt] = v;
            m = fmaxf(m, v);
        }
        #pragma unroll
        for (int off = 1; off < 16; off <<= 1) m = fmaxf(m, __shfl_xor(m, off));
        float sum = 0.f;
        #pragma unroll
        for (int nt = 0; nt < 4; nt++) { pv[nt] = __expf(pv[nt] - m); sum += pv[nt]; }
        #pragma unroll
        for (int off = 1; off < 16; off <<= 1) sum += __shfl_xor(sum, off);
        float inv = 1.0f / sum;
        #pragma unroll
        for (int nt = 0; nt < 4; nt++)
            p_s[row * PS + nt * 16 + (lane & 15)] = f2bf(pv[nt] * inv);
    }
    __syncthreads();

    // O = P @ V (rows wv*16..+16, cols 0..31)
    f32x4_t o[2] = {zero, zero};
    #pragma unroll
    for (int kt = 0; kt < 2; kt++) {
        bf16x8_t ap = *(const bf16x8_t*)&p_s[(wv * 16 + (lane & 15)) * PS + kt * 32 + (lane >> 4) * 8];
        #pragma unroll
        for (int nt = 0; nt < 2; nt++) {
            bf16x8_t bv = *(const bf16x8_t*)&vT_s[(nt * 16 + (lane & 15)) * VS + kt * 32 + (lane >> 4) * 8];
            o[nt] = __builtin_amdgcn_mfma_f32_16x16x32_bf16(ap, bv, o[nt], 0, 0, 0);
        }
    }
    // compact write: aout[((w*16+head)*49 + row)*32 + col]
    u16* obase = aout + ((size_t)(w * 16 + head)) * 49 * 32;
    #pragma unroll
    for (int nt = 0; nt < 2; nt++) {
        #pragma unroll
        for (int r = 0; r < 4; r++) {
            int row = wv * 16 + (lane >> 4) * 4 + r;
            if (row < 49)
                obase[row * 32 + nt * 16 + (lane & 15)] = f2bf(o[nt][r]);
        }
    }
}

// ------------------ window-reverse + residual + LayerNorm2 (fused) ------------------
__global__ __launch_bounds__(256) void wrev_ln(const float* __restrict__ x,
        const u16* __restrict__ aout, const float* __restrict__ g,
        const float* __restrict__ bt, float* __restrict__ x2, u16* __restrict__ h) {
    int lane = threadIdx.x & 63, wvv = threadIdx.x >> 6;
    int m = blockIdx.x * 4 + wvv;
    int b = m / N_, n = m - b * N_;
    int iy = n / Ww, ix = n - iy * Ww;
    int w = b * 64 + (iy / 7) * 8 + (ix / 7);
    int pos = (iy % 7) * 7 + (ix % 7);
    int head = lane >> 2, d0 = (lane & 3) * 8;
    u16x8 ao = *(const u16x8*)&aout[(((size_t)w * 16 + head) * 49 + pos) * 32 + d0];
    const float4* xr = (const float4*)(x + (size_t)m * C_ + lane * 8);
    float4 a = xr[0], c = xr[1];
    float v[8];
    v[0] = a.x + bf2f(ao[0]); v[1] = a.y + bf2f(ao[1]);
    v[2] = a.z + bf2f(ao[2]); v[3] = a.w + bf2f(ao[3]);
    v[4] = c.x + bf2f(ao[4]); v[5] = c.y + bf2f(ao[5]);
    v[6] = c.z + bf2f(ao[6]); v[7] = c.w + bf2f(ao[7]);
    float s = 0.f, ss = 0.f;
    #pragma unroll
    for (int jj = 0; jj < 8; jj++) { s += v[jj]; ss += v[jj] * v[jj]; }
    #pragma unroll
    for (int off = 1; off < 64; off <<= 1) {
        s  += __shfl_xor(s, off);
        ss += __shfl_xor(ss, off);
    }
    float mean = s * (1.0f / C_);
    float var  = ss * (1.0f / C_) - mean * mean;
    float rstd = rsqrtf(var + 1e-5f);
    float4 o0 = {v[0], v[1], v[2], v[3]}, o1 = {v[4], v[5], v[6], v[7]};
    float4* x2r = (float4*)(x2 + (size_t)m * C_ + lane * 8);
    x2r[0] = o0; x2r[1] = o1;
    const float4* g4 = (const float4*)(g + lane * 8);
    const float4* b4 = (const float4*)(bt + lane * 8);
    float4 g0 = g4[0], g1 = g4[1], bb0 = b4[0], bb1 = b4[1];
    u16x8 o;
    o[0] = f2bf((v[0] - mean) * rstd * g0.x + bb0.x);
    o[1] = f2bf((v[1] - mean) * rstd * g0.y + bb0.y);
    o[2] = f2bf((v[2] - mean) * rstd * g0.z + bb0.z);
    o[3] = f2bf((v[3] - mean) * rstd * g0.w + bb0.w);
    o[4] = f2bf((v[4] - mean) * rstd * g1.x + bb1.x);
    o[5] = f2bf((v[5] - mean) * rstd * g1.y + bb1.y);
    o[6] = f2bf((v[6] - mean) * rstd * g1.z + bb1.z);
    o[7] = f2bf((v[7] - mean) * rstd * g1.w + bb1.w);
    *(u16x8*)&h[(size_t)m * C_ + lane * 8] = o;
}

// ------------------ depthwise 3x3 conv + bias + exact GELU (y-pair blocked) ------------------
// XCD-striped decode: each XCD owns 4 (b,xq) column-stripes with yp ascending,
// so the 2x vertical halo re-read of `in` hits that XCD's L2 instead of HBM.
__global__ __launch_bounds__(256) void dwconv_gelu(const u16* __restrict__ in,
        const float* __restrict__ w, const float* __restrict__ bias, u16* __restrict__ out) {
    const int t = threadIdx.x;
    const int blk = blockIdx.x;
    const int xcd = blk & 7;
    const int j = blk >> 3;          // 0..111
    const int yp = j % 28;
    const int combo = j / 28;        // 0..3
    const int gl = xcd * 4 + combo;  // (b,xq) in 0..31
    const int b = gl >> 2;
    const int xq = gl & 3;
    const int y0 = yp * 2;
    const int c0 = t * 8;

    float wr[9][8];
    #pragma unroll
    for (int k = 0; k < 9; k++)
        #pragma unroll
        for (int jj = 0; jj < 8; jj++) wr[k][jj] = w[(c0 + jj) * 9 + k];
    float bs[8];
    #pragma unroll
    for (int jj = 0; jj < 8; jj++) bs[jj] = bias[c0 + jj];

    u16x8 zerov = {0,0,0,0,0,0,0,0};
    auto ldcol = [&](int xx, u16x8* col) {
        #pragma unroll
        for (int dy = 0; dy < 4; dy++) {
            int yy = y0 + dy - 1;
            bool ok = (yy >= 0 && yy < Hh && xx >= 0 && xx < Ww);
            col[dy] = ok ? *(const u16x8*)&in[(((size_t)b * Hh + yy) * Ww + xx) * HID_ + c0] : zerov;
        }
    };

    int xs = xq * 14;
    u16x8 wA[4], wB[4], wC[4];
    ldcol(xs - 1, wA);
    ldcol(xs, wB);
    for (int x = xs; x < xs + 14; x++) {
        ldcol(x + 1, wC);
        float acc0[8], acc1[8];
        #pragma unroll
        for (int jj = 0; jj < 8; jj++) { acc0[jj] = bs[jj]; acc1[jj] = bs[jj]; }
        #pragma unroll
        for (int dy = 0; dy < 3; dy++)
            #pragma unroll
            for (int jj = 0; jj < 8; jj++) {
                acc0[jj] += bf2f(wA[dy][jj]) * wr[dy * 3 + 0][jj];
                acc0[jj] += bf2f(wB[dy][jj]) * wr[dy * 3 + 1][jj];
                acc0[jj] += bf2f(wC[dy][jj]) * wr[dy * 3 + 2][jj];
                acc1[jj] += bf2f(wA[dy + 1][jj]) * wr[dy * 3 + 0][jj];
                acc1[jj] += bf2f(wB[dy + 1][jj]) * wr[dy * 3 + 1][jj];
                acc1[jj] += bf2f(wC[dy + 1][jj]) * wr[dy * 3 + 2][jj];
            }
        u16x8 o0, o1;
        #pragma unroll
        for (int jj = 0; jj < 8; jj++) {
            float v0 = acc0[jj];
            o0[jj] = f2bf(0.5f * v0 * (1.0f + erff(v0 * 0.70710678118654752f)));
            float v1 = acc1[jj];
            o1[jj] = f2bf(0.5f * v1 * (1.0f + erff(v1 * 0.70710678118654752f)));
        }
        *(u16x8*)&out[(((size_t)b * Hh + y0) * Ww + x) * HID_ + c0] = o0;
        *(u16x8*)&out[(((size_t)b * Hh + y0 + 1) * Ww + x) * HID_ + c0] = o1;
        #pragma unroll
        for (int dy = 0; dy < 4; dy++) { wA[dy] = wB[dy]; wB[dy] = wC[dy]; }
    }
}

// ------------------ launch ------------------
extern "C" void kernel_launch(void* const* d_in, const int* in_sizes, int n_in,
                              void* d_out, int out_size, void* d_ws, size_t ws_size,
                              hipStream_t stream) {
    const float* x    = (const float*)d_in[0];
    const float* n1g  = (const float*)d_in[3];
    const float* n1b  = (const float*)d_in[4];
    const float* n2g  = (const float*)d_in[5];
    const float* n2b  = (const float*)d_in[6];
    const float* qkvw = (const float*)d_in[7];
    const float* qkvb = (const float*)d_in[8];
    const float* rpb  = (const float*)d_in[9];
    const float* fc1w = (const float*)d_in[10];
    const float* fc1b = (const float*)d_in[11];
    const float* dww  = (const float*)d_in[12];
    const float* dwb  = (const float*)d_in[13];
    const float* fc2w = (const float*)d_in[14];
    const float* fc2b = (const float*)d_in[15];

    char* ws = (char*)d_ws;
    float* x2  = (float*)(ws);
    u16*   h   = (u16*)(ws + 51380224);
    u16*   qkvo= (u16*)(ws + 77070336);
    u16*   aout= (u16*)(ws + 154140672);
    u16*   f1o = (u16*)(ws + 154140672);
    u16*   cvo = (u16*)(ws + 51380224);
    u16*   wq  = (u16*)(ws + 256901120);
    u16*   w1  = (u16*)(ws + 256901120 + 1572864);
    u16*   w2  = (u16*)(ws + 256901120 + 1572864 + 2097152);

    auto ggrid = [](int nGroups) { return 32 * ((nGroups + 7) / 8); };

    // fused weight-cvt + LN1
    cvt_ln<<<dim3(M_ / 4 + 4096), dim3(256), 0, stream>>>(
        x, n1g, n1b, h, qkvw, fc1w, fc2w, wq, w1, w2);
    // qkv (short K=512): 128^2 reg-staged, nbm=196, nbn=12, nGroups=588
    gemm_bt<false, true><<<dim3(ggrid(588)), dim3(256), 0, stream>>>(
        h, wq, qkvb, nullptr, (void*)qkvo, M_, 1536, 512, 196, 12, 588);
    attn_kernel<<<dim3(B_ * 64 * NH_), dim3(256), 0, stream>>>(qkvo, rpb, aout);
    wrev_ln<<<dim3(M_ / 4), dim3(256), 0, stream>>>(x, aout, n2g, n2b, x2, h);
    // fc1 (short K=512): 128^2 reg-staged, nbm=196, nbn=16, nGroups=784
    gemm_bt<false, true><<<dim3(ggrid(784)), dim3(256), 0, stream>>>(
        h, w1, fc1b, nullptr, (void*)f1o, M_, 2048, 512, 196, 16, 784);
    dwconv_gelu<<<dim3(B_ * 28 * 4), dim3(256), 0, stream>>>(f1o, dww, dwb, cvo);
    // fc2 (long K=2048): 256^2 4-phase, 98x2 = 196 blocks
    gemm256<true, false><<<dim3(196), dim3(512), 0, stream>>>(
        cvo, w2, fc2b, x2, d_out, M_, 512, 2048, 98, 2);
}